// Round 17
// baseline (786.297 us; speedup 1.0000x reference)
//
#include <hip/hip_runtime.h>
#include <math.h>

// Problem constants (fixed by setup_inputs)
#define B_ 4
#define S_ 2048
#define D_ 512
#define H_ 8
#define E_ 64
#define M_ 2048
#define L_ 4
#define R_ (B_ * S_)          // 8192 tokens
#define RD_ ((size_t)R_ * D_) // 4,194,304 elements

typedef unsigned short u16;
typedef short short8 __attribute__((ext_vector_type(8)));
typedef float f32x4 __attribute__((ext_vector_type(4)));

__device__ __forceinline__ float4 ldg4(const float* p) {
    return *reinterpret_cast<const float4*>(p);
}
__device__ __forceinline__ float gelu_f(float x) {
    return 0.5f * x * (1.0f + erff(x * 0.70710678118654752440f));
}
// HW packed f32x2 -> bf16x2 (RNE). lo -> bits[15:0], hi -> bits[31:16].
__device__ __forceinline__ unsigned int cvt_pk_bf16(float lo, float hi) {
    unsigned int r;
    asm("v_cvt_pk_bf16_f32 %0, %1, %2" : "=v"(r) : "v"(lo), "v"(hi));
    return r;
}
// Single-instruction 2^x via the compiler-visible builtin (TRANS hazard-safe;
// raw inline-asm v_exp_f32 bypassed the hazard recognizer -> stale reads, r8).
__device__ __forceinline__ float fast_exp2(float x) {
    return __builtin_amdgcn_exp2f(x);
}
__device__ __forceinline__ float bf2f(u16 u) {
    union { unsigned int i; float f; } v; v.i = ((unsigned int)u) << 16;
    return v.f;
}
// Async global->LDS 16B/lane. LDS dest = wave-uniform base + lane*16 (linear);
// global src is per-lane. CK-style addrspace casts via uintptr_t.
__device__ __forceinline__ void async_copy16(const u16* g, u16* l) {
    auto* gp = reinterpret_cast<const __attribute__((address_space(1))) unsigned int*>(
        reinterpret_cast<uintptr_t>(g));
    auto* lp = reinterpret_cast<__attribute__((address_space(3))) unsigned int*>(
        reinterpret_cast<uintptr_t>(l));
    __builtin_amdgcn_global_load_lds(gp, lp, 16, 0, 0);
}

// ---------------------------------------------------------------------------
// bf16 MFMA GEMM, m97 structure: C[M,N] = A[M,K] @ W[N,K]^T. 128 x NB tile,
// BK=32, 4 waves. Used for qkv (EPI 0, ldc=1536) only.
// ---------------------------------------------------------------------------
template <int EPI, int NB, int BK>
__global__ __launch_bounds__(256) void gemm_bf16(
    const u16* __restrict__ A, const u16* __restrict__ W,
    const float* __restrict__ bias, const float* __restrict__ res,
    const float* __restrict__ dwp, float* __restrict__ Cf,
    u16* __restrict__ Cb, int M, int N, int K, int ldc)
{
    constexpr int TN  = NB / 32;
    constexpr int KK  = BK / 32;
    constexpr int C8  = BK / 8;
    constexpr int NA  = (128 * BK) / 2048;
    constexpr int NBc = (NB * BK) / 2048;
    constexpr int RSTEP = 2048 / BK;

    __shared__ __align__(16) u16 As[2][128 * BK];
    __shared__ __align__(16) u16 Bs[2][NB * BK];

    const int t  = threadIdx.x;
    const int w  = t >> 6, l = t & 63;
    const int lr = l & 15, g = l >> 4;
    const int wr = (w >> 1) * 64, wc = (w & 1) * (NB / 2);
    const int bm = blockIdx.x * 128, bn = blockIdx.y * NB;

    const int crow = t / C8;
    const int ccol = (t % C8) * 8;

    f32x4 acc[4][TN];
#pragma unroll
    for (int m = 0; m < 4; ++m)
#pragma unroll
        for (int n = 0; n < TN; ++n) acc[m][n] = (f32x4){0.f, 0.f, 0.f, 0.f};

    const u16* gA = A + (size_t)(bm + crow) * K + ccol;
    const u16* gB = W + (size_t)(bn + crow) * K + ccol;

    {
        u16* ab = &As[0][0];
#pragma unroll
        for (int k = 0; k < NA; ++k)
            async_copy16(gA + (size_t)(k * RSTEP) * K, ab + (t + 256 * k) * 8);
        u16* bb = &Bs[0][0];
#pragma unroll
        for (int k = 0; k < NBc; ++k)
            async_copy16(gB + (size_t)(k * RSTEP) * K, bb + (t + 256 * k) * 8);
    }
    __syncthreads();

    const int NT = K / BK;
    int cur = 0;
    for (int kt = 0; kt < NT; ++kt) {
        if (kt + 1 < NT) {
            const int off = (kt + 1) * BK;
            u16* ab = &As[cur ^ 1][0];
#pragma unroll
            for (int k = 0; k < NA; ++k)
                async_copy16(gA + (size_t)(k * RSTEP) * K + off, ab + (t + 256 * k) * 8);
            u16* bb = &Bs[cur ^ 1][0];
#pragma unroll
            for (int k = 0; k < NBc; ++k)
                async_copy16(gB + (size_t)(k * RSTEP) * K + off, bb + (t + 256 * k) * 8);
        }
        short8 af[4][KK], bfv[TN][KK];
#pragma unroll
        for (int m = 0; m < 4; ++m)
#pragma unroll
            for (int kk = 0; kk < KK; ++kk)
                af[m][kk] = *reinterpret_cast<const short8*>(
                    &As[cur][(wr + m * 16 + lr) * BK + kk * 32 + g * 8]);
#pragma unroll
        for (int n = 0; n < TN; ++n)
#pragma unroll
            for (int kk = 0; kk < KK; ++kk)
                bfv[n][kk] = *reinterpret_cast<const short8*>(
                    &Bs[cur][(wc + n * 16 + lr) * BK + kk * 32 + g * 8]);
#pragma unroll
        for (int kk = 0; kk < KK; ++kk)
#pragma unroll
            for (int m = 0; m < 4; ++m)
#pragma unroll
                for (int n = 0; n < TN; ++n)
                    acc[m][n] = __builtin_amdgcn_mfma_f32_16x16x32_bf16(
                        af[m][kk], bfv[n][kk], acc[m][n], 0, 0, 0);
        __syncthreads();
        cur ^= 1;
    }

    float sc1 = 1.f;
    if constexpr (EPI == 1) sc1 = 1.f - dwp[0];
    float bcolv[TN];
#pragma unroll
    for (int n = 0; n < TN; ++n) bcolv[n] = 0.f;
    if constexpr (EPI >= 1) {
#pragma unroll
        for (int n = 0; n < TN; ++n) bcolv[n] = bias[bn + wc + n * 16 + lr];
    }
#pragma unroll
    for (int m = 0; m < 4; ++m) {
        const int row0 = bm + wr + m * 16 + g * 4;
#pragma unroll
        for (int n = 0; n < TN; ++n) {
            const int col = bn + wc + n * 16 + lr;
            float vv[4];
#pragma unroll
            for (int q = 0; q < 4; ++q) {
                const int row = row0 + q;
                float v = acc[m][n][q];
                if constexpr (EPI >= 1) v += bcolv[n];
                if constexpr (EPI == 1) v = v * sc1 + res[(size_t)row * N + col];
                if constexpr (EPI == 2) v = gelu_f(v);
                if constexpr (EPI == 3) v += res[(size_t)row * N + col];
                if constexpr (EPI == 1 || EPI == 3) Cf[(size_t)row * N + col] = v;
                vv[q] = v;
            }
            const unsigned int pa = cvt_pk_bf16(vv[0], vv[1]);
            const unsigned int pb = cvt_pk_bf16(vv[2], vv[3]);
            Cb[(size_t)(row0 + 0) * ldc + col] = (u16)pa;
            Cb[(size_t)(row0 + 1) * ldc + col] = (u16)(pa >> 16);
            Cb[(size_t)(row0 + 2) * ldc + col] = (u16)pb;
            Cb[(size_t)(row0 + 3) * ldc + col] = (u16)(pb >> 16);
        }
    }
}

// ---------------------------------------------------------------------------
// bf16 MFMA GEMM, BM=256 x NB, BK=32, 512 threads / 8 waves (4x2 wave grid;
// wave owns 64 x NB/2). Higher FLOP/staged-byte than the 128-tile (85 at
// NB=128, 52 at NB=64 vs 44-64). NB=64 -> grid (M/256, N/64); B staging has
// only 256 chunks so threads >=256 skip it (wave-uniform).
// EPI 1: v=(acc+bias)*(1-dw)+res; Cf,Cb      (Wo)
// EPI 2: v=gelu(acc+bias); Cb                (W1)
// EPI 3: v=acc+bias+res; Cf,Cb               (W2)
// ---------------------------------------------------------------------------
template <int EPI, int NB>
__global__ __launch_bounds__(512) void gemm_bm256(
    const u16* __restrict__ A, const u16* __restrict__ W,
    const float* __restrict__ bias, const float* __restrict__ res,
    const float* __restrict__ dwp, float* __restrict__ Cf,
    u16* __restrict__ Cb, int M, int N, int K, int ldc)
{
    constexpr int TN  = NB / 32;      // 4 or 2
    constexpr int BCH = NB * 4;       // B 16B-chunks per K-step (512 or 256)
    __shared__ __align__(16) u16 As[2][256 * 32];
    __shared__ __align__(16) u16 Bs[2][NB * 32];

    const int t  = threadIdx.x;          // 0..511
    const int w  = t >> 6, l = t & 63;
    const int lr = l & 15, g = l >> 4;
    const int wr = (w >> 1) * 64;        // 0,64,128,192
    const int wc = (w & 1) * (NB / 2);
    const int bm = blockIdx.x * 256, bn = blockIdx.y * NB;

    f32x4 acc[4][TN];
#pragma unroll
    for (int m = 0; m < 4; ++m)
#pragma unroll
        for (int n = 0; n < TN; ++n) acc[m][n] = (f32x4){0.f, 0.f, 0.f, 0.f};

    const u16* gA0 = A + (size_t)(bm + (t >> 2)) * K + (t & 3) * 8;
    const u16* gA1 = A + (size_t)(bm + 128 + (t >> 2)) * K + (t & 3) * 8;
    const u16* gB  = W + (size_t)(bn + ((t >> 2) & (NB - 1))) * K + (t & 3) * 8;
    const bool doB = (t < BCH);

    {
        async_copy16(gA0, &As[0][0] + t * 8);
        async_copy16(gA1, &As[0][0] + t * 8 + 4096);
        if (doB) async_copy16(gB, &Bs[0][0] + t * 8);
    }
    __syncthreads();

    const int NT = K >> 5;
    int cur = 0;
    for (int kt = 0; kt < NT; ++kt) {
        if (kt + 1 < NT) {
            const int off = (kt + 1) << 5;
            async_copy16(gA0 + off, &As[cur ^ 1][0] + t * 8);
            async_copy16(gA1 + off, &As[cur ^ 1][0] + t * 8 + 4096);
            if (doB) async_copy16(gB + off, &Bs[cur ^ 1][0] + t * 8);
        }
        short8 af[4], bfv[TN];
#pragma unroll
        for (int m = 0; m < 4; ++m)
            af[m] = *reinterpret_cast<const short8*>(
                &As[cur][(wr + m * 16 + lr) * 32 + g * 8]);
#pragma unroll
        for (int n = 0; n < TN; ++n)
            bfv[n] = *reinterpret_cast<const short8*>(
                &Bs[cur][(wc + n * 16 + lr) * 32 + g * 8]);
#pragma unroll
        for (int m = 0; m < 4; ++m)
#pragma unroll
            for (int n = 0; n < TN; ++n)
                acc[m][n] = __builtin_amdgcn_mfma_f32_16x16x32_bf16(
                    af[m], bfv[n], acc[m][n], 0, 0, 0);
        __syncthreads();
        cur ^= 1;
    }

    float sc1 = 1.f;
    if constexpr (EPI == 1) sc1 = 1.f - dwp[0];
    float bcolv[TN];
#pragma unroll
    for (int n = 0; n < TN; ++n) bcolv[n] = bias[bn + wc + n * 16 + lr];
#pragma unroll
    for (int m = 0; m < 4; ++m) {
        const int row0 = bm + wr + m * 16 + g * 4;
#pragma unroll
        for (int n = 0; n < TN; ++n) {
            const int col = bn + wc + n * 16 + lr;
            float vv[4];
#pragma unroll
            for (int q = 0; q < 4; ++q) {
                const int row = row0 + q;
                float v = acc[m][n][q] + bcolv[n];
                if constexpr (EPI == 1) v = v * sc1 + res[(size_t)row * N + col];
                if constexpr (EPI == 2) v = gelu_f(v);
                if constexpr (EPI == 3) v += res[(size_t)row * N + col];
                if constexpr (EPI == 1 || EPI == 3) Cf[(size_t)row * N + col] = v;
                vv[q] = v;
            }
            const unsigned int pa = cvt_pk_bf16(vv[0], vv[1]);
            const unsigned int pb = cvt_pk_bf16(vv[2], vv[3]);
            Cb[(size_t)(row0 + 0) * ldc + col] = (u16)pa;
            Cb[(size_t)(row0 + 1) * ldc + col] = (u16)(pa >> 16);
            Cb[(size_t)(row0 + 2) * ldc + col] = (u16)pb;
            Cb[(size_t)(row0 + 3) * ldc + col] = (u16)(pb >> 16);
        }
    }
}

// ---------------------------------------------------------------------------
// Differential flash attention, bf16 MFMA, bf16 QKV input (stride 1536).
// O (bf16, [R,512]) = softmax(Q0K0^T/sqrt32)V - dw*softmax(Q1K1^T/sqrt32)V
// 8 waves / 512 threads; 128 q-rows per block. TRANSPOSED dataflow.
// Ks/Vt double-buffered -> ONE barrier per k-tile. (Round-13 proven loop.)
// ---------------------------------------------------------------------------
#define LDSW 72
#define QKVLD 1536
__global__ __launch_bounds__(512) void attn_mfma(
    const u16* __restrict__ QKV, u16* __restrict__ O,
    const float* __restrict__ dwp)
{
    __shared__ __align__(16) u16 Ks[2][64][LDSW];
    __shared__ __align__(16) u16 Vt[2][64][LDSW];   // row e, col k ^ (e & 56)
    __shared__ __align__(16) u16 Ps[128][LDSW];     // row q, col key (wave-private rows)

    const int t   = threadIdx.x;
    const int w   = t >> 6;
    const int l   = t & 63;
    const int lr  = l & 15;
    const int g   = l >> 4;
    const int lk8 = g << 3;

    // XCD-chunked dispatch swizzle: dispatch d -> xcd = d&7 owns bh = xcd*4 + ...
    const int d   = blockIdx.y * 16 + blockIdx.x;
    const int s   = d >> 3;
    const int bh  = (d & 7) * 4 + (s >> 4);
    const int qt  = s & 15;                 // 128-row q tile index
    const int b   = bh >> 3, h = bh & 7;

    const float dw = dwp[0];
    const float C = 0.17677669529663687f * 1.44269504088896340736f; // log2e/sqrt(32)
    const size_t tokbase = (size_t)b * S_;

    // Q fragments from global, pre-scaled by C (bf16 re-round)
    const u16* qrow = QKV + (tokbase + (size_t)(qt * 128 + w * 16 + lr)) * QKVLD + h * E_;
    short8 qf[2];
    {
        short8 qr0 = *reinterpret_cast<const short8*>(qrow + lk8);
        short8 qr1 = *reinterpret_cast<const short8*>(qrow + 32 + lk8);
        uint4 u0, u1;
        u0.x = cvt_pk_bf16(bf2f((u16)qr0[0]) * C, bf2f((u16)qr0[1]) * C);
        u0.y = cvt_pk_bf16(bf2f((u16)qr0[2]) * C, bf2f((u16)qr0[3]) * C);
        u0.z = cvt_pk_bf16(bf2f((u16)qr0[4]) * C, bf2f((u16)qr0[5]) * C);
        u0.w = cvt_pk_bf16(bf2f((u16)qr0[6]) * C, bf2f((u16)qr0[7]) * C);
        u1.x = cvt_pk_bf16(bf2f((u16)qr1[0]) * C, bf2f((u16)qr1[1]) * C);
        u1.y = cvt_pk_bf16(bf2f((u16)qr1[2]) * C, bf2f((u16)qr1[3]) * C);
        u1.z = cvt_pk_bf16(bf2f((u16)qr1[4]) * C, bf2f((u16)qr1[5]) * C);
        u1.w = cvt_pk_bf16(bf2f((u16)qr1[6]) * C, bf2f((u16)qr1[7]) * C);
        qf[0] = *reinterpret_cast<short8*>(&u0);
        qf[1] = *reinterpret_cast<short8*>(&u1);
    }

    float lsum[2] = {0.f, 0.f};
    f32x4 oacc[2][4];
#pragma unroll
    for (int c = 0; c < 2; ++c)
#pragma unroll
        for (int et = 0; et < 4; ++et) oacc[c][et] = (f32x4){0.f, 0.f, 0.f, 0.f};

    // staging: 512 threads cover 64 keys x 64 dims, 8 elements each
    const int sr   = t >> 3;           // 0..63 key/dim row
    const int sc0  = (t & 7) << 3;     // 0,8,...,56
    const int prow = w * 16 + lr;      // P^T row (this lane's q)
    const int vbit = lr & 8;           // read-side swizzle bit3
    const int vcol = sr ^ sc0;         // store col: k ^ (e & 56), e = sc0+i

    const u16* kbase = QKV + tokbase * QKVLD + h * E_ + 512 + sc0;

    // prologue: stage tile kt=0 into buf 0
    {
        const u16* kp = kbase + (size_t)sr * QKVLD;
        short8 kv = *reinterpret_cast<const short8*>(kp);
        short8 vv = *reinterpret_cast<const short8*>(kp + 512);
        *reinterpret_cast<short8*>(&Ks[0][sr][sc0]) = kv;
#pragma unroll
        for (int i = 0; i < 8; ++i)
            Vt[0][sc0 + i][vcol] = (u16)vv[i];
    }
    __syncthreads();

    const int NT = S_ / 64;
    int cur = 0;
    short8 kv_n, vv_n;
    for (int kt = 0; kt < NT; ++kt) {
        const bool pf = (kt + 1 < NT);
        if (pf) {   // issue kt+1 loads now; latency hides under compute(kt)
            const u16* kp = kbase + (size_t)((kt + 1) * 64 + sr) * QKVLD;
            kv_n = *reinterpret_cast<const short8*>(kp);
            vv_n = *reinterpret_cast<const short8*>(kp + 512);
        }

        // V fragments: read ONCE per kt, shared by both components
        short8 vfr[4][2];
#pragma unroll
        for (int et = 0; et < 4; ++et) {
            const int vx = (et << 4) ^ vbit;
            vfr[et][0] = *reinterpret_cast<const short8*>(&Vt[cur][et * 16 + lr][lk8 ^ vx]);
            vfr[et][1] = *reinterpret_cast<const short8*>(&Vt[cur][et * 16 + lr][(32 + lk8) ^ vx]);
        }

#pragma unroll
        for (int c = 0; c < 2; ++c) {
            // S^T tiles: A = K (row = key local), B = Qc (col = q local)
            f32x4 sacc[4];
            const f32x4 zf = (f32x4){0.f, 0.f, 0.f, 0.f};
#pragma unroll
            for (int kc = 0; kc < 4; ++kc) {
                short8 kf = *reinterpret_cast<const short8*>(&Ks[cur][kc * 16 + lr][c * 32 + lk8]);
                sacc[kc] = __builtin_amdgcn_mfma_f32_16x16x32_bf16(kf, qf[c], zf, 0, 0, 0);
            }
            // p = 2^s; lane holds q=lr, keys kc*16 + g*4 + {0..3}
            float ls = 0.f;
#pragma unroll
            for (int kc = 0; kc < 4; ++kc) {
                float p0 = fast_exp2(sacc[kc][0]);
                float p1 = fast_exp2(sacc[kc][1]);
                float p2 = fast_exp2(sacc[kc][2]);
                float p3 = fast_exp2(sacc[kc][3]);
                ls += (p0 + p1) + (p2 + p3);
                uint2 pk;
                pk.x = cvt_pk_bf16(p0, p1);
                pk.y = cvt_pk_bf16(p2, p3);
                *reinterpret_cast<uint2*>(&Ps[prow][kc * 16 + (g << 2)]) = pk;
            }
            lsum[c] += ls;
            // PV: O^T = V^T @ P^T (A = Vt fragments, B = own wave's P^T rows)
            short8 pf0 = *reinterpret_cast<const short8*>(&Ps[prow][lk8]);
            short8 pf1 = *reinterpret_cast<const short8*>(&Ps[prow][32 + lk8]);
#pragma unroll
            for (int et = 0; et < 4; ++et) {
                oacc[c][et] = __builtin_amdgcn_mfma_f32_16x16x32_bf16(vfr[et][0], pf0, oacc[c][et], 0, 0, 0);
                oacc[c][et] = __builtin_amdgcn_mfma_f32_16x16x32_bf16(vfr[et][1], pf1, oacc[c][et], 0, 0, 0);
            }
        }

        if (pf) {
            // write kt+1 tile into the buffer all waves finished reading
            // before the PREVIOUS barrier (cur^1) -> single barrier suffices
            *reinterpret_cast<short8*>(&Ks[cur ^ 1][sr][sc0]) = kv_n;
#pragma unroll
            for (int i = 0; i < 8; ++i)
                Vt[cur ^ 1][sc0 + i][vcol] = (u16)vv_n[i];
            __syncthreads();   // kt+1 tile visible to all waves
        }
        cur ^= 1;
    }

    // reduce l across the 4 key-quad groups (lanes same lr)
#pragma unroll
    for (int c = 0; c < 2; ++c) {
        lsum[c] += __shfl_xor(lsum[c], 16, 64);
        lsum[c] += __shfl_xor(lsum[c], 32, 64);
    }
    const float inv0 = 1.f / lsum[0];
    const float inv1 = dw / lsum[1];

    // epilogue: lane holds q = qt*128 + w*16 + lr, e = et*16 + g*4 + {0..3}
    const size_t row = tokbase + (size_t)(qt * 128 + w * 16 + lr);
    u16* op = O + row * D_ + h * E_ + (g << 2);
#pragma unroll
    for (int et = 0; et < 4; ++et) {
        uint2 ov;
        ov.x = cvt_pk_bf16(oacc[0][et][0] * inv0 - oacc[1][et][0] * inv1,
                           oacc[0][et][1] * inv0 - oacc[1][et][1] * inv1);
        ov.y = cvt_pk_bf16(oacc[0][et][2] * inv0 - oacc[1][et][2] * inv1,
                           oacc[0][et][3] * inv0 - oacc[1][et][3] * inv1);
        *reinterpret_cast<uint2*>(op + et * 16) = ov;
    }
}

// ---------------------------------------------------------------------------
// Per-token RMSNorm over D=512, bf16 in-place, fp32 weight.
// ---------------------------------------------------------------------------
__global__ __launch_bounds__(256) void rmsnorm_bf(
    u16* __restrict__ X, const float* __restrict__ rw)
{
    const int row  = (blockIdx.x << 2) + (threadIdx.x >> 6);
    const int lane = threadIdx.x & 63;
    u16* xp = X + (size_t)row * D_ + lane * 8;
    short8 xv = *reinterpret_cast<const short8*>(xp);
    float xf[8];
#pragma unroll
    for (int i = 0; i < 8; ++i) xf[i] = bf2f((u16)xv[i]);
    float q = 0.f;
#pragma unroll
    for (int i = 0; i < 8; ++i) q += xf[i] * xf[i];
#pragma unroll
    for (int o = 1; o < 64; o <<= 1) q += __shfl_xor(q, o, 64);
    const float rstd = rsqrtf(q * (1.0f / 512.0f) + 1.1920929e-07f);
    const float* wp = rw + lane * 8;
    float4 w0 = ldg4(wp), w1 = ldg4(wp + 4);
    uint4 yv;
    yv.x = cvt_pk_bf16(xf[0] * rstd * w0.x, xf[1] * rstd * w0.y);
    yv.y = cvt_pk_bf16(xf[2] * rstd * w0.z, xf[3] * rstd * w0.w);
    yv.z = cvt_pk_bf16(xf[4] * rstd * w1.x, xf[5] * rstd * w1.y);
    yv.w = cvt_pk_bf16(xf[6] * rstd * w1.z, xf[7] * rstd * w1.w);
    *reinterpret_cast<uint4*>(xp) = yv;
}

// ---------------------------------------------------------------------------
// Per-token LayerNorm over D=512, fp32 in. OUT=0: fp32 out; OUT=1: bf16 out.
// ---------------------------------------------------------------------------
template <int OUT>
__global__ __launch_bounds__(256) void layernorm_k(
    const float* __restrict__ X, const float* __restrict__ g,
    const float* __restrict__ bb, float* __restrict__ Yf,
    u16* __restrict__ Yb, float eps)
{
    const int row  = (blockIdx.x << 2) + (threadIdx.x >> 6);
    const int lane = threadIdx.x & 63;
    const float* xp = X + (size_t)row * D_;
    float4 x0 = ldg4(xp + lane * 4);
    float4 x1 = ldg4(xp + 256 + lane * 4);

    float s = x0.x + x0.y + x0.z + x0.w + x1.x + x1.y + x1.z + x1.w;
#pragma unroll
    for (int o = 1; o < 64; o <<= 1) s += __shfl_xor(s, o, 64);
    const float mean = s * (1.0f / 512.0f);

    x0.x -= mean; x0.y -= mean; x0.z -= mean; x0.w -= mean;
    x1.x -= mean; x1.y -= mean; x1.z -= mean; x1.w -= mean;
    float q = x0.x * x0.x + x0.y * x0.y + x0.z * x0.z + x0.w * x0.w
            + x1.x * x1.x + x1.y * x1.y + x1.z * x1.z + x1.w * x1.w;
#pragma unroll
    for (int o = 1; o < 64; o <<= 1) q += __shfl_xor(q, o, 64);
    const float rstd = rsqrtf(q * (1.0f / 512.0f) + eps);

    float4 g0 = ldg4(g + lane * 4),  g1 = ldg4(g + 256 + lane * 4);
    float4 b0 = ldg4(bb + lane * 4), b1 = ldg4(bb + 256 + lane * 4);
    float y[8];
    y[0] = x0.x * rstd * g0.x + b0.x; y[1] = x0.y * rstd * g0.y + b0.y;
    y[2] = x0.z * rstd * g0.z + b0.z; y[3] = x0.w * rstd * g0.w + b0.w;
    y[4] = x1.x * rstd * g1.x + b1.x; y[5] = x1.y * rstd * g1.y + b1.y;
    y[6] = x1.z * rstd * g1.z + b1.z; y[7] = x1.w * rstd * g1.w + b1.w;
    if constexpr (OUT == 0) {
        float* yp = Yf + (size_t)row * D_;
        *reinterpret_cast<float4*>(yp + lane * 4)       = make_float4(y[0], y[1], y[2], y[3]);
        *reinterpret_cast<float4*>(yp + 256 + lane * 4) = make_float4(y[4], y[5], y[6], y[7]);
    } else {
        u16* yp = Yb + (size_t)row * D_;
        uint2 a, b;
        a.x = cvt_pk_bf16(y[0], y[1]); a.y = cvt_pk_bf16(y[2], y[3]);
        b.x = cvt_pk_bf16(y[4], y[5]); b.y = cvt_pk_bf16(y[6], y[7]);
        *reinterpret_cast<uint2*>(yp + lane * 4)       = a;
        *reinterpret_cast<uint2*>(yp + 256 + lane * 4) = b;
    }
}

// ---------------------------------------------------------------------------
// init: xc = x (f32), xcb = bf16(x)
// ---------------------------------------------------------------------------
__global__ __launch_bounds__(256) void initcvt(
    const float* __restrict__ x, float* __restrict__ xc, u16* __restrict__ xcb)
{
    const size_t i = ((size_t)blockIdx.x * 256 + threadIdx.x) * 4;
    float4 v = ldg4(x + i);
    *reinterpret_cast<float4*>(xc + i) = v;
    uint2 o;
    o.x = cvt_pk_bf16(v.x, v.y); o.y = cvt_pk_bf16(v.z, v.w);
    *reinterpret_cast<uint2*>(xcb + i) = o;
}

// ---------------------------------------------------------------------------
// ALL-layer weight convert fp32 -> bf16 in ONE launch. Per layer: wqkv
// stacked [1536,512] (786432 el), wo 262144, w1 1048576, w2 1048576.
// Grid = 4 layers x 3072 blocks.
// ---------------------------------------------------------------------------
__global__ __launch_bounds__(256) void conv_all_w(
    const float* __restrict__ Wq, const float* __restrict__ Wk,
    const float* __restrict__ Wv, const float* __restrict__ Wo,
    const float* __restrict__ W1, const float* __restrict__ W2,
    u16* __restrict__ wqkv, u16* __restrict__ wo,
    u16* __restrict__ w1, u16* __restrict__ w2)
{
    const int lidx = blockIdx.x / 3072;
    const size_t i = ((size_t)(blockIdx.x % 3072) * 256 + threadIdx.x) * 4;
    const float* src; u16* dst;
    if (i < 786432) {
        dst = wqkv + (size_t)lidx * 786432 + i;
        if (i < 262144)      src = Wq + (size_t)lidx * 262144 + i;
        else if (i < 524288) src = Wk + (size_t)lidx * 262144 + (i - 262144);
        else                 src = Wv + (size_t)lidx * 262144 + (i - 524288);
    } else if (i < 1048576) {
        src = Wo + (size_t)lidx * 262144 + (i - 786432);
        dst = wo + (size_t)lidx * 262144 + (i - 786432);
    } else if (i < 2097152) {
        src = W1 + (size_t)lidx * 1048576 + (i - 1048576);
        dst = w1 + (size_t)lidx * 1048576 + (i - 1048576);
    } else {
        src = W2 + (size_t)lidx * 1048576 + (i - 2097152);
        dst = w2 + (size_t)lidx * 1048576 + (i - 2097152);
    }
    float4 v = ldg4(src);
    uint2 o;
    o.x = cvt_pk_bf16(v.x, v.y); o.y = cvt_pk_bf16(v.z, v.w);
    *reinterpret_cast<uint2*>(dst) = o;
}

// ---------------------------------------------------------------------------
extern "C" void kernel_launch(void* const* d_in, const int* in_sizes, int n_in,
                              void* d_out, int out_size, void* d_ws, size_t ws_size,
                              hipStream_t stream)
{
    const float* x     = (const float*)d_in[0];
    const float* Wq    = (const float*)d_in[1];
    const float* Wk    = (const float*)d_in[2];
    const float* Wv    = (const float*)d_in[3];
    const float* rms_w = (const float*)d_in[4];
    const float* Wo    = (const float*)d_in[5];
    const float* bo    = (const float*)d_in[6];
    const float* diffw = (const float*)d_in[7];
    const float* g_ffn = (const float*)d_in[8];
    const float* b_ffn = (const float*)d_in[9];
    const float* W1    = (const float*)d_in[10];
    const float* b1    = (const float*)d_in[11];
    const float* W2    = (const float*)d_in[12];
    const float* b2    = (const float*)d_in[13];
    const float* g_f   = (const float*)d_in[14];
    const float* b_f   = (const float*)d_in[15];

    // workspace layout (bytes):
    char* ws = (char*)d_ws;
    float* xc    = (float*)(ws);                   // 16,777,216 B
    u16*   xcb   = (u16*)(ws + 16777216);          //  8,388,608 B
    u16*   qkvb  = (u16*)(ws + 25165824);          // 25,165,824 B  [R,1536]
    u16*   ob    = (u16*)(ws + 50331648);          //  8,388,608 B  [R,512]
    u16*   tb    = qkvb;                           // [R,512]  (qkv dead after attn)
    u16*   hb    = (u16*)(ws + 33554432);          // [R,2048] spans qkv tail+ob+extra
    u16*   wqkvA = (u16*)(ws + 67108864);          //  6,291,456 B [4][1536,512]
    u16*   wo_A  = (u16*)(ws + 73400320);          //  2,097,152 B [4][512,512]
    u16*   w1_A  = (u16*)(ws + 75497472);          //  8,388,608 B [4][2048,512]
    u16*   w2_A  = (u16*)(ws + 83886080);          //  8,388,608 B [4][512,2048]
    // total 92,274,688 B

    const dim3 blk(256);
    initcvt<<<dim3(RD_ / 4 / 256), blk, 0, stream>>>(x, xc, xcb);
    conv_all_w<<<dim3(4 * 3072), blk, 0, stream>>>(
        Wq, Wk, Wv, Wo, W1, W2, wqkvA, wo_A, w1_A, w2_A);

    const dim3 g_tok(R_ / 4);

    for (int l = 0; l < L_; ++l) {
        const float* bo_l = bo + (size_t)l * D_;
        const float* b1_l = b1 + (size_t)l * M_;
        const float* b2_l = b2 + (size_t)l * D_;
        const float* dw_l = diffw + l;
        const u16* wqkv_l = wqkvA + (size_t)l * 786432;
        const u16* wo_l   = wo_A  + (size_t)l * 262144;
        const u16* w1_l   = w1_A  + (size_t)l * 1048576;
        const u16* w2_l   = w2_A  + (size_t)l * 1048576;

        // qkv = xcb @ wqkv^T   [8192, 1536]
        gemm_bf16<0, 128, 32><<<dim3(R_ / 128, 12), blk, 0, stream>>>(
            xcb, wqkv_l, nullptr, nullptr, nullptr, nullptr, qkvb,
            R_, 1536, D_, 1536);

        attn_mfma<<<dim3(S_ / 128, B_ * H_), dim3(512), 0, stream>>>(qkvb, ob, dw_l);

        rmsnorm_bf<<<g_tok, blk, 0, stream>>>(ob, rms_w + (size_t)l * D_);

        // xc = (ob @ wo^T + bo)*(1-dw) + xc ; xcb = bf16(xc)   [BM=256 x 64]
        gemm_bm256<1, 64><<<dim3(R_ / 256, D_ / 64), dim3(512), 0, stream>>>(
            ob, wo_l, bo_l, xc, dw_l, xc, xcb, R_, D_, D_, D_);

        // tb = bf16(LN(xc))
        layernorm_k<1><<<g_tok, blk, 0, stream>>>(
            xc, g_ffn + (size_t)l * D_, b_ffn + (size_t)l * D_, nullptr, tb, 1e-5f);

        // hb = gelu(tb @ w1^T + b1)   [BM=256 x NB=128, 512 threads]
        gemm_bm256<2, 128><<<dim3(R_ / 256, M_ / 128), dim3(512), 0, stream>>>(
            tb, w1_l, b1_l, nullptr, nullptr, nullptr, hb, R_, M_, D_, M_);

        // xc = hb @ w2^T + b2 + xc ; xcb = bf16(xc)   [BM=256 x 64]
        gemm_bm256<3, 64><<<dim3(R_ / 256, D_ / 64), dim3(512), 0, stream>>>(
            hb, w2_l, b2_l, xc, nullptr, xc, xcb, R_, D_, M_, D_);
    }

    layernorm_k<0><<<g_tok, blk, 0, stream>>>(xc, g_f, b_f, (float*)d_out, nullptr, 1e-5f);
}

// Round 18
// 753.458 us; speedup vs baseline: 1.0436x; 1.0436x over previous
//
#include <hip/hip_runtime.h>
#include <math.h>

// Problem constants (fixed by setup_inputs)
#define B_ 4
#define S_ 2048
#define D_ 512
#define H_ 8
#define E_ 64
#define M_ 2048
#define L_ 4
#define R_ (B_ * S_)          // 8192 tokens
#define RD_ ((size_t)R_ * D_) // 4,194,304 elements

typedef unsigned short u16;
typedef short short8 __attribute__((ext_vector_type(8)));
typedef float f32x4 __attribute__((ext_vector_type(4)));

__device__ __forceinline__ float4 ldg4(const float* p) {
    return *reinterpret_cast<const float4*>(p);
}
__device__ __forceinline__ float gelu_f(float x) {
    return 0.5f * x * (1.0f + erff(x * 0.70710678118654752440f));
}
// HW packed f32x2 -> bf16x2 (RNE). lo -> bits[15:0], hi -> bits[31:16].
__device__ __forceinline__ unsigned int cvt_pk_bf16(float lo, float hi) {
    unsigned int r;
    asm("v_cvt_pk_bf16_f32 %0, %1, %2" : "=v"(r) : "v"(lo), "v"(hi));
    return r;
}
// Single-instruction 2^x via the compiler-visible builtin (TRANS hazard-safe;
// raw inline-asm v_exp_f32 bypassed the hazard recognizer -> stale reads, r8).
__device__ __forceinline__ float fast_exp2(float x) {
    return __builtin_amdgcn_exp2f(x);
}
__device__ __forceinline__ float bf2f(u16 u) {
    union { unsigned int i; float f; } v; v.i = ((unsigned int)u) << 16;
    return v.f;
}
// Async global->LDS 16B/lane. LDS dest = wave-uniform base + lane*16 (linear);
// global src is per-lane. CK-style addrspace casts via uintptr_t.
__device__ __forceinline__ void async_copy16(const u16* g, u16* l) {
    auto* gp = reinterpret_cast<const __attribute__((address_space(1))) unsigned int*>(
        reinterpret_cast<uintptr_t>(g));
    auto* lp = reinterpret_cast<__attribute__((address_space(3))) unsigned int*>(
        reinterpret_cast<uintptr_t>(l));
    __builtin_amdgcn_global_load_lds(gp, lp, 16, 0, 0);
}

// ---------------------------------------------------------------------------
// bf16 MFMA GEMM, m97 structure: C[M,N] = A[M,K] @ W[N,K]^T (+ epilogue).
// Tile 128 x NB, K-step BK (32 or 64), 4 waves (2x2), wave owns 64 x NB/2.
// At NB=64/BK=64: 512 blocks = 2 blocks/CU -> inter-block barrier overlap
// (1-block/CU variants regress: every syncthreads stalls the whole CU, r17).
// EPI 0: Cb = bf16(acc)                      (qkv; ldc=1536)
// EPI 1: v=(acc+bias)*(1-dw)+res; Cf,Cb      (Wo + residual)
// EPI 3: v=acc+bias+res; Cf,Cb               (W2 + residual)
// ---------------------------------------------------------------------------
template <int EPI, int NB, int BK>
__global__ __launch_bounds__(256) void gemm_bf16(
    const u16* __restrict__ A, const u16* __restrict__ W,
    const float* __restrict__ bias, const float* __restrict__ res,
    const float* __restrict__ dwp, float* __restrict__ Cf,
    u16* __restrict__ Cb, int M, int N, int K, int ldc)
{
    constexpr int TN  = NB / 32;
    constexpr int KK  = BK / 32;
    constexpr int C8  = BK / 8;
    constexpr int NA  = (128 * BK) / 2048;
    constexpr int NBc = (NB * BK) / 2048;
    constexpr int RSTEP = 2048 / BK;

    __shared__ __align__(16) u16 As[2][128 * BK];
    __shared__ __align__(16) u16 Bs[2][NB * BK];

    const int t  = threadIdx.x;
    const int w  = t >> 6, l = t & 63;
    const int lr = l & 15, g = l >> 4;
    const int wr = (w >> 1) * 64, wc = (w & 1) * (NB / 2);
    const int bm = blockIdx.x * 128, bn = blockIdx.y * NB;

    const int crow = t / C8;
    const int ccol = (t % C8) * 8;

    f32x4 acc[4][TN];
#pragma unroll
    for (int m = 0; m < 4; ++m)
#pragma unroll
        for (int n = 0; n < TN; ++n) acc[m][n] = (f32x4){0.f, 0.f, 0.f, 0.f};

    const u16* gA = A + (size_t)(bm + crow) * K + ccol;
    const u16* gB = W + (size_t)(bn + crow) * K + ccol;

    {
        u16* ab = &As[0][0];
#pragma unroll
        for (int k = 0; k < NA; ++k)
            async_copy16(gA + (size_t)(k * RSTEP) * K, ab + (t + 256 * k) * 8);
        u16* bb = &Bs[0][0];
#pragma unroll
        for (int k = 0; k < NBc; ++k)
            async_copy16(gB + (size_t)(k * RSTEP) * K, bb + (t + 256 * k) * 8);
    }
    __syncthreads();

    const int NT = K / BK;
    int cur = 0;
    for (int kt = 0; kt < NT; ++kt) {
        if (kt + 1 < NT) {
            const int off = (kt + 1) * BK;
            u16* ab = &As[cur ^ 1][0];
#pragma unroll
            for (int k = 0; k < NA; ++k)
                async_copy16(gA + (size_t)(k * RSTEP) * K + off, ab + (t + 256 * k) * 8);
            u16* bb = &Bs[cur ^ 1][0];
#pragma unroll
            for (int k = 0; k < NBc; ++k)
                async_copy16(gB + (size_t)(k * RSTEP) * K + off, bb + (t + 256 * k) * 8);
        }
        short8 af[4][KK], bfv[TN][KK];
#pragma unroll
        for (int m = 0; m < 4; ++m)
#pragma unroll
            for (int kk = 0; kk < KK; ++kk)
                af[m][kk] = *reinterpret_cast<const short8*>(
                    &As[cur][(wr + m * 16 + lr) * BK + kk * 32 + g * 8]);
#pragma unroll
        for (int n = 0; n < TN; ++n)
#pragma unroll
            for (int kk = 0; kk < KK; ++kk)
                bfv[n][kk] = *reinterpret_cast<const short8*>(
                    &Bs[cur][(wc + n * 16 + lr) * BK + kk * 32 + g * 8]);
#pragma unroll
        for (int kk = 0; kk < KK; ++kk)
#pragma unroll
            for (int m = 0; m < 4; ++m)
#pragma unroll
                for (int n = 0; n < TN; ++n)
                    acc[m][n] = __builtin_amdgcn_mfma_f32_16x16x32_bf16(
                        af[m][kk], bfv[n][kk], acc[m][n], 0, 0, 0);
        __syncthreads();
        cur ^= 1;
    }

    float sc1 = 1.f;
    if constexpr (EPI == 1) sc1 = 1.f - dwp[0];
    float bcolv[TN];
#pragma unroll
    for (int n = 0; n < TN; ++n) bcolv[n] = 0.f;
    if constexpr (EPI >= 1) {
#pragma unroll
        for (int n = 0; n < TN; ++n) bcolv[n] = bias[bn + wc + n * 16 + lr];
    }
#pragma unroll
    for (int m = 0; m < 4; ++m) {
        const int row0 = bm + wr + m * 16 + g * 4;
#pragma unroll
        for (int n = 0; n < TN; ++n) {
            const int col = bn + wc + n * 16 + lr;
            float vv[4];
#pragma unroll
            for (int q = 0; q < 4; ++q) {
                const int row = row0 + q;
                float v = acc[m][n][q];
                if constexpr (EPI >= 1) v += bcolv[n];
                if constexpr (EPI == 1) v = v * sc1 + res[(size_t)row * N + col];
                if constexpr (EPI == 2) v = gelu_f(v);
                if constexpr (EPI == 3) v += res[(size_t)row * N + col];
                if constexpr (EPI == 1 || EPI == 3) Cf[(size_t)row * N + col] = v;
                vv[q] = v;
            }
            const unsigned int pa = cvt_pk_bf16(vv[0], vv[1]);
            const unsigned int pb = cvt_pk_bf16(vv[2], vv[3]);
            Cb[(size_t)(row0 + 0) * ldc + col] = (u16)pa;
            Cb[(size_t)(row0 + 1) * ldc + col] = (u16)(pa >> 16);
            Cb[(size_t)(row0 + 2) * ldc + col] = (u16)pb;
            Cb[(size_t)(row0 + 3) * ldc + col] = (u16)(pb >> 16);
        }
    }
}

// ---------------------------------------------------------------------------
// bf16 MFMA GEMM, BM=256 x NB=128, BK=32, 512 threads / 8 waves (4x2 grid;
// wave owns 64x64). 85 FLOP/staged-byte; grid (M/256, N/128) -> 2 blocks/CU
// for W1. EPI 2: v = gelu(acc + bias); Cb = bf16(v).
// ---------------------------------------------------------------------------
template <int EPI>
__global__ __launch_bounds__(512) void gemm_bm256(
    const u16* __restrict__ A, const u16* __restrict__ W,
    const float* __restrict__ bias, u16* __restrict__ Cb,
    int M, int N, int K, int ldc)
{
    __shared__ __align__(16) u16 As[2][256 * 32];
    __shared__ __align__(16) u16 Bs[2][128 * 32];

    const int t  = threadIdx.x;          // 0..511
    const int w  = t >> 6, l = t & 63;
    const int lr = l & 15, g = l >> 4;
    const int wr = (w >> 1) * 64;        // 0,64,128,192
    const int wc = (w & 1) * 64;
    const int bm = blockIdx.x * 256, bn = blockIdx.y * 128;

    f32x4 acc[4][4];
#pragma unroll
    for (int m = 0; m < 4; ++m)
#pragma unroll
        for (int n = 0; n < 4; ++n) acc[m][n] = (f32x4){0.f, 0.f, 0.f, 0.f};

    const u16* gA0 = A + (size_t)(bm + (t >> 2)) * K + (t & 3) * 8;
    const u16* gA1 = A + (size_t)(bm + 128 + (t >> 2)) * K + (t & 3) * 8;
    const u16* gB  = W + (size_t)(bn + (t >> 2)) * K + (t & 3) * 8;

    {
        async_copy16(gA0, &As[0][0] + t * 8);
        async_copy16(gA1, &As[0][0] + t * 8 + 4096);
        async_copy16(gB,  &Bs[0][0] + t * 8);
    }
    __syncthreads();

    const int NT = K >> 5;
    int cur = 0;
    for (int kt = 0; kt < NT; ++kt) {
        if (kt + 1 < NT) {
            const int off = (kt + 1) << 5;
            async_copy16(gA0 + off, &As[cur ^ 1][0] + t * 8);
            async_copy16(gA1 + off, &As[cur ^ 1][0] + t * 8 + 4096);
            async_copy16(gB + off,  &Bs[cur ^ 1][0] + t * 8);
        }
        short8 af[4], bfv[4];
#pragma unroll
        for (int m = 0; m < 4; ++m)
            af[m] = *reinterpret_cast<const short8*>(
                &As[cur][(wr + m * 16 + lr) * 32 + g * 8]);
#pragma unroll
        for (int n = 0; n < 4; ++n)
            bfv[n] = *reinterpret_cast<const short8*>(
                &Bs[cur][(wc + n * 16 + lr) * 32 + g * 8]);
#pragma unroll
        for (int m = 0; m < 4; ++m)
#pragma unroll
            for (int n = 0; n < 4; ++n)
                acc[m][n] = __builtin_amdgcn_mfma_f32_16x16x32_bf16(
                    af[m], bfv[n], acc[m][n], 0, 0, 0);
        __syncthreads();
        cur ^= 1;
    }

    float bcolv[4];
#pragma unroll
    for (int n = 0; n < 4; ++n) bcolv[n] = bias[bn + wc + n * 16 + lr];
#pragma unroll
    for (int m = 0; m < 4; ++m) {
        const int row0 = bm + wr + m * 16 + g * 4;
#pragma unroll
        for (int n = 0; n < 4; ++n) {
            const int col = bn + wc + n * 16 + lr;
            float vv[4];
#pragma unroll
            for (int q = 0; q < 4; ++q) {
                float v = acc[m][n][q] + bcolv[n];
                if constexpr (EPI == 2) v = gelu_f(v);
                vv[q] = v;
            }
            const unsigned int pa = cvt_pk_bf16(vv[0], vv[1]);
            const unsigned int pb = cvt_pk_bf16(vv[2], vv[3]);
            Cb[(size_t)(row0 + 0) * ldc + col] = (u16)pa;
            Cb[(size_t)(row0 + 1) * ldc + col] = (u16)(pa >> 16);
            Cb[(size_t)(row0 + 2) * ldc + col] = (u16)pb;
            Cb[(size_t)(row0 + 3) * ldc + col] = (u16)(pb >> 16);
        }
    }
}

// ---------------------------------------------------------------------------
// Differential flash attention, bf16 MFMA, bf16 QKV input (stride 1536).
// O (bf16, [R,512]) = softmax(Q0K0^T/sqrt32)V - dw*softmax(Q1K1^T/sqrt32)V
// 8 waves / 512 threads; 128 q-rows per block. TRANSPOSED dataflow.
// Ks/Vt double-buffered -> ONE barrier per k-tile (round-13 proven loop).
// NEW: s_setprio(1) around MFMA clusters — 2 unsynced blocks/CU give the
// scheduler phase diversity to arbitrate (T5-positive regime).
// ---------------------------------------------------------------------------
#define LDSW 72
#define QKVLD 1536
__global__ __launch_bounds__(512) void attn_mfma(
    const u16* __restrict__ QKV, u16* __restrict__ O,
    const float* __restrict__ dwp)
{
    __shared__ __align__(16) u16 Ks[2][64][LDSW];
    __shared__ __align__(16) u16 Vt[2][64][LDSW];   // row e, col k ^ (e & 56)
    __shared__ __align__(16) u16 Ps[128][LDSW];     // row q, col key (wave-private rows)

    const int t   = threadIdx.x;
    const int w   = t >> 6;
    const int l   = t & 63;
    const int lr  = l & 15;
    const int g   = l >> 4;
    const int lk8 = g << 3;

    // XCD-chunked dispatch swizzle: dispatch d -> xcd = d&7 owns bh = xcd*4 + ...
    const int d   = blockIdx.y * 16 + blockIdx.x;
    const int s   = d >> 3;
    const int bh  = (d & 7) * 4 + (s >> 4);
    const int qt  = s & 15;                 // 128-row q tile index
    const int b   = bh >> 3, h = bh & 7;

    const float dw = dwp[0];
    const float C = 0.17677669529663687f * 1.44269504088896340736f; // log2e/sqrt(32)
    const size_t tokbase = (size_t)b * S_;

    // Q fragments from global, pre-scaled by C (bf16 re-round)
    const u16* qrow = QKV + (tokbase + (size_t)(qt * 128 + w * 16 + lr)) * QKVLD + h * E_;
    short8 qf[2];
    {
        short8 qr0 = *reinterpret_cast<const short8*>(qrow + lk8);
        short8 qr1 = *reinterpret_cast<const short8*>(qrow + 32 + lk8);
        uint4 u0, u1;
        u0.x = cvt_pk_bf16(bf2f((u16)qr0[0]) * C, bf2f((u16)qr0[1]) * C);
        u0.y = cvt_pk_bf16(bf2f((u16)qr0[2]) * C, bf2f((u16)qr0[3]) * C);
        u0.z = cvt_pk_bf16(bf2f((u16)qr0[4]) * C, bf2f((u16)qr0[5]) * C);
        u0.w = cvt_pk_bf16(bf2f((u16)qr0[6]) * C, bf2f((u16)qr0[7]) * C);
        u1.x = cvt_pk_bf16(bf2f((u16)qr1[0]) * C, bf2f((u16)qr1[1]) * C);
        u1.y = cvt_pk_bf16(bf2f((u16)qr1[2]) * C, bf2f((u16)qr1[3]) * C);
        u1.z = cvt_pk_bf16(bf2f((u16)qr1[4]) * C, bf2f((u16)qr1[5]) * C);
        u1.w = cvt_pk_bf16(bf2f((u16)qr1[6]) * C, bf2f((u16)qr1[7]) * C);
        qf[0] = *reinterpret_cast<short8*>(&u0);
        qf[1] = *reinterpret_cast<short8*>(&u1);
    }

    float lsum[2] = {0.f, 0.f};
    f32x4 oacc[2][4];
#pragma unroll
    for (int c = 0; c < 2; ++c)
#pragma unroll
        for (int et = 0; et < 4; ++et) oacc[c][et] = (f32x4){0.f, 0.f, 0.f, 0.f};

    // staging: 512 threads cover 64 keys x 64 dims, 8 elements each
    const int sr   = t >> 3;           // 0..63 key/dim row
    const int sc0  = (t & 7) << 3;     // 0,8,...,56
    const int prow = w * 16 + lr;      // P^T row (this lane's q)
    const int vbit = lr & 8;           // read-side swizzle bit3
    const int vcol = sr ^ sc0;         // store col: k ^ (e & 56), e = sc0+i

    const u16* kbase = QKV + tokbase * QKVLD + h * E_ + 512 + sc0;

    // prologue: stage tile kt=0 into buf 0
    {
        const u16* kp = kbase + (size_t)sr * QKVLD;
        short8 kv = *reinterpret_cast<const short8*>(kp);
        short8 vv = *reinterpret_cast<const short8*>(kp + 512);
        *reinterpret_cast<short8*>(&Ks[0][sr][sc0]) = kv;
#pragma unroll
        for (int i = 0; i < 8; ++i)
            Vt[0][sc0 + i][vcol] = (u16)vv[i];
    }
    __syncthreads();

    const int NT = S_ / 64;
    int cur = 0;
    short8 kv_n, vv_n;
    for (int kt = 0; kt < NT; ++kt) {
        const bool pf = (kt + 1 < NT);
        if (pf) {   // issue kt+1 loads now; latency hides under compute(kt)
            const u16* kp = kbase + (size_t)((kt + 1) * 64 + sr) * QKVLD;
            kv_n = *reinterpret_cast<const short8*>(kp);
            vv_n = *reinterpret_cast<const short8*>(kp + 512);
        }

        // V fragments: read ONCE per kt, shared by both components
        short8 vfr[4][2];
#pragma unroll
        for (int et = 0; et < 4; ++et) {
            const int vx = (et << 4) ^ vbit;
            vfr[et][0] = *reinterpret_cast<const short8*>(&Vt[cur][et * 16 + lr][lk8 ^ vx]);
            vfr[et][1] = *reinterpret_cast<const short8*>(&Vt[cur][et * 16 + lr][(32 + lk8) ^ vx]);
        }

#pragma unroll
        for (int c = 0; c < 2; ++c) {
            // S^T tiles: A = K (row = key local), B = Qc (col = q local)
            f32x4 sacc[4];
            const f32x4 zf = (f32x4){0.f, 0.f, 0.f, 0.f};
            __builtin_amdgcn_s_setprio(1);
#pragma unroll
            for (int kc = 0; kc < 4; ++kc) {
                short8 kf = *reinterpret_cast<const short8*>(&Ks[cur][kc * 16 + lr][c * 32 + lk8]);
                sacc[kc] = __builtin_amdgcn_mfma_f32_16x16x32_bf16(kf, qf[c], zf, 0, 0, 0);
            }
            __builtin_amdgcn_s_setprio(0);
            // p = 2^s; lane holds q=lr, keys kc*16 + g*4 + {0..3}
            float ls = 0.f;
#pragma unroll
            for (int kc = 0; kc < 4; ++kc) {
                float p0 = fast_exp2(sacc[kc][0]);
                float p1 = fast_exp2(sacc[kc][1]);
                float p2 = fast_exp2(sacc[kc][2]);
                float p3 = fast_exp2(sacc[kc][3]);
                ls += (p0 + p1) + (p2 + p3);
                uint2 pk;
                pk.x = cvt_pk_bf16(p0, p1);
                pk.y = cvt_pk_bf16(p2, p3);
                *reinterpret_cast<uint2*>(&Ps[prow][kc * 16 + (g << 2)]) = pk;
            }
            lsum[c] += ls;
            // PV: O^T = V^T @ P^T (A = Vt fragments, B = own wave's P^T rows)
            short8 pf0 = *reinterpret_cast<const short8*>(&Ps[prow][lk8]);
            short8 pf1 = *reinterpret_cast<const short8*>(&Ps[prow][32 + lk8]);
            __builtin_amdgcn_s_setprio(1);
#pragma unroll
            for (int et = 0; et < 4; ++et) {
                oacc[c][et] = __builtin_amdgcn_mfma_f32_16x16x32_bf16(vfr[et][0], pf0, oacc[c][et], 0, 0, 0);
                oacc[c][et] = __builtin_amdgcn_mfma_f32_16x16x32_bf16(vfr[et][1], pf1, oacc[c][et], 0, 0, 0);
            }
            __builtin_amdgcn_s_setprio(0);
        }

        if (pf) {
            // write kt+1 tile into the buffer all waves finished reading
            // before the PREVIOUS barrier (cur^1) -> single barrier suffices
            *reinterpret_cast<short8*>(&Ks[cur ^ 1][sr][sc0]) = kv_n;
#pragma unroll
            for (int i = 0; i < 8; ++i)
                Vt[cur ^ 1][sc0 + i][vcol] = (u16)vv_n[i];
            __syncthreads();   // kt+1 tile visible to all waves
        }
        cur ^= 1;
    }

    // reduce l across the 4 key-quad groups (lanes same lr)
#pragma unroll
    for (int c = 0; c < 2; ++c) {
        lsum[c] += __shfl_xor(lsum[c], 16, 64);
        lsum[c] += __shfl_xor(lsum[c], 32, 64);
    }
    const float inv0 = 1.f / lsum[0];
    const float inv1 = dw / lsum[1];

    // epilogue: lane holds q = qt*128 + w*16 + lr, e = et*16 + g*4 + {0..3}
    const size_t row = tokbase + (size_t)(qt * 128 + w * 16 + lr);
    u16* op = O + row * D_ + h * E_ + (g << 2);
#pragma unroll
    for (int et = 0; et < 4; ++et) {
        uint2 ov;
        ov.x = cvt_pk_bf16(oacc[0][et][0] * inv0 - oacc[1][et][0] * inv1,
                           oacc[0][et][1] * inv0 - oacc[1][et][1] * inv1);
        ov.y = cvt_pk_bf16(oacc[0][et][2] * inv0 - oacc[1][et][2] * inv1,
                           oacc[0][et][3] * inv0 - oacc[1][et][3] * inv1);
        *reinterpret_cast<uint2*>(op + et * 16) = ov;
    }
}

// ---------------------------------------------------------------------------
// Per-token RMSNorm over D=512, bf16 in-place, fp32 weight.
// ---------------------------------------------------------------------------
__global__ __launch_bounds__(256) void rmsnorm_bf(
    u16* __restrict__ X, const float* __restrict__ rw)
{
    const int row  = (blockIdx.x << 2) + (threadIdx.x >> 6);
    const int lane = threadIdx.x & 63;
    u16* xp = X + (size_t)row * D_ + lane * 8;
    short8 xv = *reinterpret_cast<const short8*>(xp);
    float xf[8];
#pragma unroll
    for (int i = 0; i < 8; ++i) xf[i] = bf2f((u16)xv[i]);
    float q = 0.f;
#pragma unroll
    for (int i = 0; i < 8; ++i) q += xf[i] * xf[i];
#pragma unroll
    for (int o = 1; o < 64; o <<= 1) q += __shfl_xor(q, o, 64);
    const float rstd = rsqrtf(q * (1.0f / 512.0f) + 1.1920929e-07f);
    const float* wp = rw + lane * 8;
    float4 w0 = ldg4(wp), w1 = ldg4(wp + 4);
    uint4 yv;
    yv.x = cvt_pk_bf16(xf[0] * rstd * w0.x, xf[1] * rstd * w0.y);
    yv.y = cvt_pk_bf16(xf[2] * rstd * w0.z, xf[3] * rstd * w0.w);
    yv.z = cvt_pk_bf16(xf[4] * rstd * w1.x, xf[5] * rstd * w1.y);
    yv.w = cvt_pk_bf16(xf[6] * rstd * w1.z, xf[7] * rstd * w1.w);
    *reinterpret_cast<uint4*>(xp) = yv;
}

// ---------------------------------------------------------------------------
// Per-token LayerNorm over D=512, fp32 in. OUT=0: fp32 out; OUT=1: bf16 out.
// ---------------------------------------------------------------------------
template <int OUT>
__global__ __launch_bounds__(256) void layernorm_k(
    const float* __restrict__ X, const float* __restrict__ g,
    const float* __restrict__ bb, float* __restrict__ Yf,
    u16* __restrict__ Yb, float eps)
{
    const int row  = (blockIdx.x << 2) + (threadIdx.x >> 6);
    const int lane = threadIdx.x & 63;
    const float* xp = X + (size_t)row * D_;
    float4 x0 = ldg4(xp + lane * 4);
    float4 x1 = ldg4(xp + 256 + lane * 4);

    float s = x0.x + x0.y + x0.z + x0.w + x1.x + x1.y + x1.z + x1.w;
#pragma unroll
    for (int o = 1; o < 64; o <<= 1) s += __shfl_xor(s, o, 64);
    const float mean = s * (1.0f / 512.0f);

    x0.x -= mean; x0.y -= mean; x0.z -= mean; x0.w -= mean;
    x1.x -= mean; x1.y -= mean; x1.z -= mean; x1.w -= mean;
    float q = x0.x * x0.x + x0.y * x0.y + x0.z * x0.z + x0.w * x0.w
            + x1.x * x1.x + x1.y * x1.y + x1.z * x1.z + x1.w * x1.w;
#pragma unroll
    for (int o = 1; o < 64; o <<= 1) q += __shfl_xor(q, o, 64);
    const float rstd = rsqrtf(q * (1.0f / 512.0f) + eps);

    float4 g0 = ldg4(g + lane * 4),  g1 = ldg4(g + 256 + lane * 4);
    float4 b0 = ldg4(bb + lane * 4), b1 = ldg4(bb + 256 + lane * 4);
    float y[8];
    y[0] = x0.x * rstd * g0.x + b0.x; y[1] = x0.y * rstd * g0.y + b0.y;
    y[2] = x0.z * rstd * g0.z + b0.z; y[3] = x0.w * rstd * g0.w + b0.w;
    y[4] = x1.x * rstd * g1.x + b1.x; y[5] = x1.y * rstd * g1.y + b1.y;
    y[6] = x1.z * rstd * g1.z + b1.z; y[7] = x1.w * rstd * g1.w + b1.w;
    if constexpr (OUT == 0) {
        float* yp = Yf + (size_t)row * D_;
        *reinterpret_cast<float4*>(yp + lane * 4)       = make_float4(y[0], y[1], y[2], y[3]);
        *reinterpret_cast<float4*>(yp + 256 + lane * 4) = make_float4(y[4], y[5], y[6], y[7]);
    } else {
        u16* yp = Yb + (size_t)row * D_;
        uint2 a, b;
        a.x = cvt_pk_bf16(y[0], y[1]); a.y = cvt_pk_bf16(y[2], y[3]);
        b.x = cvt_pk_bf16(y[4], y[5]); b.y = cvt_pk_bf16(y[6], y[7]);
        *reinterpret_cast<uint2*>(yp + lane * 4)       = a;
        *reinterpret_cast<uint2*>(yp + 256 + lane * 4) = b;
    }
}

// ---------------------------------------------------------------------------
// init: xc = x (f32), xcb = bf16(x)
// ---------------------------------------------------------------------------
__global__ __launch_bounds__(256) void initcvt(
    const float* __restrict__ x, float* __restrict__ xc, u16* __restrict__ xcb)
{
    const size_t i = ((size_t)blockIdx.x * 256 + threadIdx.x) * 4;
    float4 v = ldg4(x + i);
    *reinterpret_cast<float4*>(xc + i) = v;
    uint2 o;
    o.x = cvt_pk_bf16(v.x, v.y); o.y = cvt_pk_bf16(v.z, v.w);
    *reinterpret_cast<uint2*>(xcb + i) = o;
}

// ---------------------------------------------------------------------------
// ALL-layer weight convert fp32 -> bf16 in ONE launch. Per layer: wqkv
// stacked [1536,512] (786432 el), wo 262144, w1 1048576, w2 1048576.
// Grid = 4 layers x 3072 blocks.
// ---------------------------------------------------------------------------
__global__ __launch_bounds__(256) void conv_all_w(
    const float* __restrict__ Wq, const float* __restrict__ Wk,
    const float* __restrict__ Wv, const float* __restrict__ Wo,
    const float* __restrict__ W1, const float* __restrict__ W2,
    u16* __restrict__ wqkv, u16* __restrict__ wo,
    u16* __restrict__ w1, u16* __restrict__ w2)
{
    const int lidx = blockIdx.x / 3072;
    const size_t i = ((size_t)(blockIdx.x % 3072) * 256 + threadIdx.x) * 4;
    const float* src; u16* dst;
    if (i < 786432) {
        dst = wqkv + (size_t)lidx * 786432 + i;
        if (i < 262144)      src = Wq + (size_t)lidx * 262144 + i;
        else if (i < 524288) src = Wk + (size_t)lidx * 262144 + (i - 262144);
        else                 src = Wv + (size_t)lidx * 262144 + (i - 524288);
    } else if (i < 1048576) {
        src = Wo + (size_t)lidx * 262144 + (i - 786432);
        dst = wo + (size_t)lidx * 262144 + (i - 786432);
    } else if (i < 2097152) {
        src = W1 + (size_t)lidx * 1048576 + (i - 1048576);
        dst = w1 + (size_t)lidx * 1048576 + (i - 1048576);
    } else {
        src = W2 + (size_t)lidx * 1048576 + (i - 2097152);
        dst = w2 + (size_t)lidx * 1048576 + (i - 2097152);
    }
    float4 v = ldg4(src);
    uint2 o;
    o.x = cvt_pk_bf16(v.x, v.y); o.y = cvt_pk_bf16(v.z, v.w);
    *reinterpret_cast<uint2*>(dst) = o;
}

// ---------------------------------------------------------------------------
extern "C" void kernel_launch(void* const* d_in, const int* in_sizes, int n_in,
                              void* d_out, int out_size, void* d_ws, size_t ws_size,
                              hipStream_t stream)
{
    const float* x     = (const float*)d_in[0];
    const float* Wq    = (const float*)d_in[1];
    const float* Wk    = (const float*)d_in[2];
    const float* Wv    = (const float*)d_in[3];
    const float* rms_w = (const float*)d_in[4];
    const float* Wo    = (const float*)d_in[5];
    const float* bo    = (const float*)d_in[6];
    const float* diffw = (const float*)d_in[7];
    const float* g_ffn = (const float*)d_in[8];
    const float* b_ffn = (const float*)d_in[9];
    const float* W1    = (const float*)d_in[10];
    const float* b1    = (const float*)d_in[11];
    const float* W2    = (const float*)d_in[12];
    const float* b2    = (const float*)d_in[13];
    const float* g_f   = (const float*)d_in[14];
    const float* b_f   = (const float*)d_in[15];

    // workspace layout (bytes):
    char* ws = (char*)d_ws;
    float* xc    = (float*)(ws);                   // 16,777,216 B
    u16*   xcb   = (u16*)(ws + 16777216);          //  8,388,608 B
    u16*   qkvb  = (u16*)(ws + 25165824);          // 25,165,824 B  [R,1536]
    u16*   ob    = (u16*)(ws + 50331648);          //  8,388,608 B  [R,512]
    u16*   tb    = qkvb;                           // [R,512]  (qkv dead after attn)
    u16*   hb    = (u16*)(ws + 33554432);          // [R,2048] spans qkv tail+ob+extra
    u16*   wqkvA = (u16*)(ws + 67108864);          //  6,291,456 B [4][1536,512]
    u16*   wo_A  = (u16*)(ws + 73400320);          //  2,097,152 B [4][512,512]
    u16*   w1_A  = (u16*)(ws + 75497472);          //  8,388,608 B [4][2048,512]
    u16*   w2_A  = (u16*)(ws + 83886080);          //  8,388,608 B [4][512,2048]
    // total 92,274,688 B

    const dim3 blk(256);
    initcvt<<<dim3(RD_ / 4 / 256), blk, 0, stream>>>(x, xc, xcb);
    conv_all_w<<<dim3(4 * 3072), blk, 0, stream>>>(
        Wq, Wk, Wv, Wo, W1, W2, wqkvA, wo_A, w1_A, w2_A);

    const dim3 g_tok(R_ / 4);

    for (int l = 0; l < L_; ++l) {
        const float* bo_l = bo + (size_t)l * D_;
        const float* b1_l = b1 + (size_t)l * M_;
        const float* b2_l = b2 + (size_t)l * D_;
        const float* dw_l = diffw + l;
        const u16* wqkv_l = wqkvA + (size_t)l * 786432;
        const u16* wo_l   = wo_A  + (size_t)l * 262144;
        const u16* w1_l   = w1_A  + (size_t)l * 1048576;
        const u16* w2_l   = w2_A  + (size_t)l * 1048576;

        // qkv = xcb @ wqkv^T   [8192, 1536]
        gemm_bf16<0, 128, 32><<<dim3(R_ / 128, 12), blk, 0, stream>>>(
            xcb, wqkv_l, nullptr, nullptr, nullptr, nullptr, qkvb,
            R_, 1536, D_, 1536);

        attn_mfma<<<dim3(S_ / 128, B_ * H_), dim3(512), 0, stream>>>(qkvb, ob, dw_l);

        rmsnorm_bf<<<g_tok, blk, 0, stream>>>(ob, rms_w + (size_t)l * D_);

        // xc = (ob @ wo^T + bo)*(1-dw) + xc ; xcb = bf16(xc)   [128x64, BK=64]
        gemm_bf16<1, 64, 64><<<dim3(R_ / 128, 8), blk, 0, stream>>>(
            ob, wo_l, bo_l, xc, dw_l, xc, xcb, R_, D_, D_, D_);

        // tb = bf16(LN(xc))
        layernorm_k<1><<<g_tok, blk, 0, stream>>>(
            xc, g_ffn + (size_t)l * D_, b_ffn + (size_t)l * D_, nullptr, tb, 1e-5f);

        // hb = gelu(tb @ w1^T + b1)   [BM=256 x NB=128, 512 threads]
        gemm_bm256<2><<<dim3(R_ / 256, M_ / 128), dim3(512), 0, stream>>>(
            tb, w1_l, b1_l, hb, R_, M_, D_, M_);

        // xc = hb @ w2^T + b2 + xc ; xcb = bf16(xc)   [128x64, BK=64]
        gemm_bf16<3, 64, 64><<<dim3(R_ / 128, 8), blk, 0, stream>>>(
            hb, w2_l, b2_l, xc, nullptr, xc, xcb, R_, D_, M_, D_);
    }

    layernorm_k<0><<<g_tok, blk, 0, stream>>>(xc, g_f, b_f, (float*)d_out, nullptr, 1e-5f);
}